// Round 14
// baseline (485.468 us; speedup 1.0000x reference)
//
#include <hip/hip_runtime.h>
#include <float.h>

#define NLVL 12
#define NB   16
#define NBLK 256      // blocks owning node chunks / count arrays
#define GEDGE 512     // grid for partitioned edge-scatter phases
#define MAXCHUNK 1024 // >= ceil(N/NBLK); N=200k -> 784

// meta: [96..109) base_f | [128..141) base_b | [160..177) base_o
// packed entry: id(18b) | fl(4b)<<18 | bl(4b)<<22 | tidx(4b)<<26   (N=200k < 2^18)
// tidx = nt*3+ninv in 0..8 -> h_init row = tabg[tidx]  (h_init never materialized)

struct Params {
    const int *nt, *ninv, *src, *dst, *fl, *bl, *batch;
    const float *We, *be, *Wf, *bf, *Wb, *bb;
    float *hN, *hB, *tabg, *out;
    int *rowptr, *cursor, *col, *nb_f, *nb_b, *onodes, *bsums, *meta, *plarr;
    int *cntf, *cntb, *cnto, *blkf, *blkb, *blko;
    int N, E, M, outN;
};

__device__ __forceinline__ float rlanef(float x, int l) {
    return __int_as_float(__builtin_amdgcn_readlane(__float_as_int(x), l));
}

// ------- degrees (XCD-partitioned, 512 blk) + per-block node histograms (256 blk) -------
__global__ void k_deg_hist(Params p) {
    __shared__ int hf[NLVL], hb[NLVL], ho[NB];
    int tid = threadIdx.x, bid = blockIdx.x;
    if (tid < NLVL) { hf[tid] = 0; hb[tid] = 0; }
    if (tid < NB) ho[tid] = 0;
    __syncthreads();
    int part = bid & 7;
    int plo = (int)(((long long)p.N * part) >> 3);
    int phi = (int)(((long long)p.N * (part + 1)) >> 3);
    int sb = bid >> 3;
    for (int e = sb * 256 + tid; e < p.E; e += (GEDGE / 8) * 256) {
        int d = p.dst[e];
        if (d >= plo && d < phi) atomicAdd(&p.rowptr[d], 1);
        int s = p.src[e];
        if (s >= plo && s < phi) atomicAdd(&p.rowptr[p.N + s], 1);
    }
    if (bid < NBLK) {
        int chunk = (p.N + NBLK - 1) / NBLK;           // same chunk map as k_fill
        int lo = bid * chunk, hi = lo + chunk; if (hi > p.N) hi = p.N;
        for (int i = lo + tid; i < hi; i += 256) {
            int f = p.fl[i], b = p.bl[i];
            int t = p.nt[i], iv = p.ninv[i];
            p.plarr[i] = f | (b << 4) | ((t * 3 + iv) << 8);
            atomicAdd(&hf[f], 1);
            atomicAdd(&hb[b], 1);
            if (t == 1) atomicAdd(&ho[p.batch[i]], 1);
        }
        __syncthreads();
        if (tid < NLVL) { p.cntf[tid * NBLK + bid] = hf[tid]; p.cntb[tid * NBLK + bid] = hb[tid]; }
        if (tid < NB) p.cnto[tid * NBLK + bid] = ho[tid];
    }
}

// ---------------- 3-kernel exclusive scan over M = 2N ----------------
__global__ void k_scan1(int* __restrict__ data, int M, int* __restrict__ bsums) {
    __shared__ int s[512];
    int t = threadIdx.x;
    int g = blockIdx.x * 512 + t;
    int v = (g < M) ? data[g] : 0;
    s[t] = v;
    __syncthreads();
    for (int off = 1; off < 512; off <<= 1) {
        int add = (t >= off) ? s[t - off] : 0;
        __syncthreads();
        s[t] += add;
        __syncthreads();
    }
    if (g < M) data[g] = s[t] - v;
    if (t == 511) bsums[blockIdx.x] = s[511];
}

// scan_top: bsums scan + per-block-base segmented scans + meta bases + tabg + out init
__global__ void k_scan_top(int* __restrict__ bsums, int nblk, Params p,
                           float* __restrict__ out, int outN) {
    __shared__ int s[1024];
    __shared__ int tot[48];     // fwd [0..12), bwd [16..28), out [32..48)
    int t = threadIdx.x;
    int* meta = p.meta;
    for (int i = t; i < outN; i += 1024)
        out[i] = ((i & 127) < 64) ? -FLT_MAX : 0.0f;   // max-pool init == finfo.min
    if (t < 576) {              // 9-row h_init table
        int row = t >> 6, j = t & 63;
        float nf = (float)(row / 3), iv = (float)(row % 3);
        p.tabg[t] = fmaf(nf, p.We[j], fmaf(iv, p.We[64 + j], p.be[j]));
    }
    int seg = t >> 8, b = t & 255;
    for (int r = 0; r < 3; r++) {
        int l = 4 * r + seg;
        int v = p.cntf[l * NBLK + b];
        s[t] = v; __syncthreads();
        for (int off = 1; off < NBLK; off <<= 1) {
            int add = (b >= off) ? s[t - off] : 0; __syncthreads();
            s[t] += add; __syncthreads();
        }
        p.blkf[l * NBLK + b] = s[t] - v;
        if (b == NBLK - 1) tot[l] = s[t];
        __syncthreads();
    }
    for (int r = 0; r < 3; r++) {
        int l = 4 * r + seg;
        int v = p.cntb[l * NBLK + b];
        s[t] = v; __syncthreads();
        for (int off = 1; off < NBLK; off <<= 1) {
            int add = (b >= off) ? s[t - off] : 0; __syncthreads();
            s[t] += add; __syncthreads();
        }
        p.blkb[l * NBLK + b] = s[t] - v;
        if (b == NBLK - 1) tot[16 + l] = s[t];
        __syncthreads();
    }
    for (int r = 0; r < 4; r++) {
        int l = 4 * r + seg;
        int v = p.cnto[l * NBLK + b];
        s[t] = v; __syncthreads();
        for (int off = 1; off < NBLK; off <<= 1) {
            int add = (b >= off) ? s[t - off] : 0; __syncthreads();
            s[t] += add; __syncthreads();
        }
        p.blko[l * NBLK + b] = s[t] - v;
        if (b == NBLK - 1) tot[32 + l] = s[t];
        __syncthreads();
    }
    if (t == 0) { int a = 0; for (int l = 0; l < NLVL; l++) { meta[96 + l] = a; a += tot[l]; } meta[96 + NLVL] = a; }
    if (t == 1) { int a = 0; for (int l = 0; l < NLVL; l++) { meta[128 + l] = a; a += tot[16 + l]; } meta[128 + NLVL] = a; }
    if (t == 2) { int a = 0; for (int l = 0; l < NB; l++) { meta[160 + l] = a; a += tot[32 + l]; } meta[160 + NB] = a; }
    __syncthreads();
    for (int i = t; i < NLVL * NBLK; i += 1024) p.blkf[i] += meta[96 + (i >> 8)];
    for (int i = t; i < NLVL * NBLK; i += 1024) p.blkb[i] += meta[128 + (i >> 8)];
    for (int i = t; i < NB * NBLK; i += 1024) p.blko[i] += meta[160 + (i >> 8)];
    int v = (t < nblk) ? bsums[t] : 0;
    s[t] = v;
    __syncthreads();
    for (int off = 1; off < 1024; off <<= 1) {
        int add = (t >= off) ? s[t - off] : 0;
        __syncthreads();
        s[t] += add;
        __syncthreads();
    }
    if (t < nblk) bsums[t] = s[t] - v;
}

__global__ void k_scan_add(int* __restrict__ rowptr, int* __restrict__ cursor, int M, int total,
                           const int* __restrict__ bsums) {
    int g = blockIdx.x * blockDim.x + threadIdx.x;
    if (g >= M) return;
    int r = rowptr[g] + bsums[g >> 9];
    rowptr[g] = r;
    cursor[g] = r;
    if (g == 0) rowptr[M] = total;
}

// ------- CSR fill (XCD-partitioned) + LDS-staged coalesced node scatter (256 blk) -------
__global__ void k_fill(Params p) {
    __shared__ int stgf[MAXCHUNK], stgb[MAXCHUNK], stgo[MAXCHUNK];
    __shared__ int lbf[NLVL + 1], lbb[NLVL + 1], lbo[NB + 1];
    __shared__ int curf[NLVL], curb[NLVL], curo[NB];
    int tid = threadIdx.x, bid = blockIdx.x;
    int N = p.N;

    // partitioned edge scatter: atomics + col stores stay XCD-local
    int part = bid & 7;
    int plo = (int)(((long long)N * part) >> 3);
    int phi = (int)(((long long)N * (part + 1)) >> 3);
    int sb = bid >> 3;
    for (int e = sb * 256 + tid; e < p.E; e += (GEDGE / 8) * 256) {
        int s = p.src[e], d = p.dst[e];
        if (d >= plo && d < phi)
            p.col[atomicAdd(&p.cursor[d], 1)] = s | (p.plarr[s] << 18);      // in-edge: other = src
        if (s >= plo && s < phi)
            p.col[atomicAdd(&p.cursor[N + s], 1)] = d | (p.plarr[d] << 18);  // out-edge: other = dst
    }

    if (bid >= NBLK) return;
    // within-block level bases from this block's own counts (tiny serial scans)
    if (tid == 0) { int a = 0; for (int l = 0; l < NLVL; l++) { lbf[l] = a; curf[l] = a; a += p.cntf[l * NBLK + bid]; } lbf[NLVL] = a; }
    if (tid == 1) { int a = 0; for (int l = 0; l < NLVL; l++) { lbb[l] = a; curb[l] = a; a += p.cntb[l * NBLK + bid]; } lbb[NLVL] = a; }
    if (tid == 2) { int a = 0; for (int l = 0; l < NB;  l++) { lbo[l] = a; curo[l] = a; a += p.cnto[l * NBLK + bid]; } lbo[NB] = a; }
    __syncthreads();
    int chunk = (N + NBLK - 1) / NBLK;
    int lo = bid * chunk, hi = lo + chunk; if (hi > N) hi = N;
    // stage into LDS ordered by level
    for (int i = lo + tid; i < hi; i += 256) {
        int pl = p.plarr[i];
        int lf = pl & 15, lb = (pl >> 4) & 15, tx = (pl >> 8) & 15;
        int pk = i | (pl << 18);
        stgf[atomicAdd(&curf[lf], 1)] = pk;
        stgb[atomicAdd(&curb[lb], 1)] = pk;
        if (tx >= 3 && tx < 6)                          // nt == 1
            stgo[atomicAdd(&curo[p.batch[i]], 1)] = pk;
    }
    __syncthreads();
    // coalesced copy-out: consecutive LDS slots within a level -> consecutive global
    int nf = lbf[NLVL], nb_ = lbb[NLVL], no = lbo[NB];
    for (int j = tid; j < nf; j += 256) {
        int l = 0;
        while (j >= lbf[l + 1]) l++;                    // <=12-step scan, VALU-cheap
        p.nb_f[p.blkf[l * NBLK + bid] + (j - lbf[l])] = stgf[j];
    }
    for (int j = tid; j < nb_; j += 256) {
        int l = 0;
        while (j >= lbb[l + 1]) l++;
        p.nb_b[p.blkb[l * NBLK + bid] + (j - lbb[l])] = stgb[j];
    }
    for (int j = tid; j < no; j += 256) {
        int l = 0;
        while (j >= lbo[l + 1]) l++;
        p.onodes[p.blko[l * NBLK + bid] + (j - lbo[l])] = stgo[j];
    }
}

// ---------------- per-level sweep: quarter-per-node gather + VALU matvec ----
// (zero DS ops; broadcast via v_readlane — champion r10/r11 code, unchanged)
__global__ __launch_bounds__(256, 4) void k_sweep(Params p, int lvl, int dir) {
    const int tid = threadIdx.x, lane = tid & 63;
    const float* W = dir ? p.Wb : p.Wf;
    float w[64];
    #pragma unroll
    for (int k = 0; k < 64; k++) w[k] = W[k * 64 + lane];
    float bv = (dir ? p.bb : p.bf)[lane];

    const int* nb = dir ? p.nb_b : p.nb_f;
    const int* rp = p.rowptr + (dir ? p.N : 0);
    int start = p.meta[(dir ? 128 : 96) + lvl];
    int cnt   = p.meta[(dir ? 128 : 96) + lvl + 1] - start;
    const int wid = (blockIdx.x * 256 + tid) >> 6;
    const int nw  = (gridDim.x * 256) >> 6;
    const int q = lane >> 4, fb = (lane & 15) * 4;
    float* db = dir ? p.hB : p.hN;

    int c0 = (int)((long long)cnt * wid / nw);
    int c1 = (int)((long long)cnt * (wid + 1) / nw);
    for (int i = c0; i < c1; i += 4) {
        int my = i + q;
        int v = 0, rpv = 0, rpe = 0;
        if (my < c1) {
            int e = nb[start + my];
            v = e & 0x3FFFF;
            rpv = rp[v]; rpe = rp[v + 1];
        }
        float4 acc = make_float4(0.f, 0.f, 0.f, 0.f);
        for (int cb = rpv; cb < rpe; cb++) {
            int cu = p.col[cb];
            int u = cu & 0x3FFFF;
            int flu = (cu >> 18) & 15, blu = (cu >> 22) & 15;
            const float* sp;
            if (dir == 0)
                sp = (flu > 0 && flu < lvl) ? (p.hN + (size_t)u * 64)
                                            : (p.tabg + ((cu >> 26) & 15) * 64);
            else
                sp = (blu > 0 && blu < lvl) ? (p.hB + (size_t)u * 64)
                   : (flu > 0)              ? (p.hN + (size_t)u * 64)
                                            : (p.tabg + ((cu >> 26) & 15) * 64);
            const float4 x = *(const float4*)(sp + fb);
            acc.x += x.x; acc.y += x.y; acc.z += x.z; acc.w += x.w;
        }
        #pragma unroll
        for (int qq = 0; qq < 4; qq++) {
            if (i + qq >= c1) break;                    // wave-uniform
            int vs   = __builtin_amdgcn_readlane(v, 16 * qq);
            int degs = __builtin_amdgcn_readlane(rpe, 16 * qq)
                     - __builtin_amdgcn_readlane(rpv, 16 * qq);
            float o = bv * (float)degs;
            #pragma unroll
            for (int m = 0; m < 16; m++) {
                float ax = rlanef(acc.x, 16 * qq + m);
                float ay = rlanef(acc.y, 16 * qq + m);
                float az = rlanef(acc.z, 16 * qq + m);
                float aw = rlanef(acc.w, 16 * qq + m);
                o = fmaf(ax, w[4 * m + 0], o);
                o = fmaf(ay, w[4 * m + 1], o);
                o = fmaf(az, w[4 * m + 2], o);
                o = fmaf(aw, w[4 * m + 3], o);
            }
            db[(size_t)vs * 64 + lane] = o;
        }
    }
}

// ---------------- readout ----------------
__device__ inline void atomicMaxF(float* addr, float val) {
    int* ai = (int*)addr;
    int old = *ai;
    while (__int_as_float(old) < val) {
        int assumed = old;
        old = atomicCAS(ai, assumed, __float_as_int(val));
        if (old == assumed) break;
    }
}

__global__ void k_readout(Params p) {
    int lane = threadIdx.x & 63;
    int b = blockIdx.x >> 5;
    int sl = blockIdx.x & 31;
    int a0 = p.meta[160 + b], a1 = p.meta[161 + b];
    int cnt = a1 - a0;
    if (cnt == 0) return;
    int lo = a0 + (int)((long long)cnt * sl / 32);
    int hi = a0 + (int)((long long)cnt * (sl + 1) / 32);
    int wcnt = hi - lo;
    int wave = threadIdx.x >> 6;
    int wl = lo + (wcnt * wave) / 4;
    int wh = lo + (wcnt * (wave + 1)) / 4;
    if (wh <= wl) return;
    float mx = -FLT_MAX, sm = 0.f;
    for (int k = wl; k < wh; k += 64) {
        int take = wh - k; if (take > 64) take = 64;
        int el = (lane < take) ? p.onodes[k + lane] : 0;
        for (int j = 0; j < take; j++) {
            int e = __shfl(el, j, 64);
            int v = e & 0x3FFFF;
            int flv = (e >> 18) & 15, blv = (e >> 22) & 15;
            const float* sp = (blv > 0) ? (p.hB + (size_t)v * 64)
                            : (flv > 0) ? (p.hN + (size_t)v * 64)
                                        : (p.tabg + ((e >> 26) & 15) * 64);
            float x = sp[lane];
            mx = fmaxf(mx, x);
            sm += x;
        }
    }
    atomicMaxF(&p.out[b * 128 + lane], mx);
    atomicAdd(&p.out[b * 128 + 64 + lane], sm);
}

extern "C" void kernel_launch(void* const* d_in, const int* in_sizes, int n_in,
                              void* d_out, int out_size, void* d_ws, size_t ws_size,
                              hipStream_t stream) {
    int N = in_sizes[0];
    int E = in_sizes[2] / 2;
    int M = 2 * N;

    Params p;
    p.nt    = (const int*)d_in[0];
    p.ninv  = (const int*)d_in[1];
    p.src   = (const int*)d_in[2];
    p.dst   = (const int*)d_in[2] + E;
    p.fl    = (const int*)d_in[3];
    p.bl    = (const int*)d_in[4];
    p.batch = (const int*)d_in[5];
    p.We    = (const float*)d_in[6];
    p.be    = (const float*)d_in[7];
    p.Wf    = (const float*)d_in[8];
    p.bf    = (const float*)d_in[9];
    p.Wb    = (const float*)d_in[10];
    p.bb    = (const float*)d_in[11];
    p.out   = (float*)d_out;
    p.N = N; p.E = E; p.M = M; p.outN = out_size;

    char* ws = (char*)d_ws;
    size_t off = 0;
    auto alloc = [&](size_t bytes) -> char* {
        char* q = ws + off;
        off = (off + bytes + 255) & ~(size_t)255;
        return q;
    };
    // rowptr + meta adjacent -> one memset zeroes both
    p.rowptr = (int*)  alloc((size_t)(M + 1) * sizeof(int));
    p.meta   = (int*)  alloc(256 * sizeof(int));
    size_t zbytes = (size_t)((char*)(p.meta + 256) - (char*)p.rowptr);
    p.hN     = (float*)alloc((size_t)N * 64 * sizeof(float));
    p.hB     = (float*)alloc((size_t)N * 64 * sizeof(float));
    p.tabg   = (float*)alloc(9 * 64 * sizeof(float));
    p.cursor = (int*)  alloc((size_t)M * sizeof(int));
    p.col    = (int*)  alloc((size_t)2 * E * sizeof(int));
    p.nb_f   = (int*)  alloc((size_t)N * sizeof(int));
    p.nb_b   = (int*)  alloc((size_t)N * sizeof(int));
    p.onodes = (int*)  alloc((size_t)N * sizeof(int));
    p.plarr  = (int*)  alloc((size_t)N * sizeof(int));
    p.bsums  = (int*)  alloc(1024 * sizeof(int));
    p.cntf   = (int*)  alloc(NLVL * NBLK * sizeof(int));
    p.cntb   = (int*)  alloc(NLVL * NBLK * sizeof(int));
    p.cnto   = (int*)  alloc(NB * NBLK * sizeof(int));
    p.blkf   = (int*)  alloc(NLVL * NBLK * sizeof(int));
    p.blkb   = (int*)  alloc(NLVL * NBLK * sizeof(int));
    p.blko   = (int*)  alloc(NB * NBLK * sizeof(int));

    int nscan = (M + 511) / 512;            // 782 <= 1024

    hipMemsetAsync(p.rowptr, 0, zbytes, stream);
    k_deg_hist<<<GEDGE, 256, 0, stream>>>(p);
    k_scan1<<<nscan, 512, 0, stream>>>(p.rowptr, M, p.bsums);
    k_scan_top<<<1, 1024, 0, stream>>>(p.bsums, nscan, p, p.out, out_size);
    k_scan_add<<<(M + 255) / 256, 256, 0, stream>>>(p.rowptr, p.cursor, M, 2 * E, p.bsums);
    k_fill<<<GEDGE, 256, 0, stream>>>(p);

    for (int l = 1; l < NLVL; l++)
        k_sweep<<<1024, 256, 0, stream>>>(p, l, 0);
    for (int l = 1; l < NLVL; l++)
        k_sweep<<<1024, 256, 0, stream>>>(p, l, 1);

    k_readout<<<NB * 32, 256, 0, stream>>>(p);
}

// Round 15
// 478.173 us; speedup vs baseline: 1.0153x; 1.0153x over previous
//
#include <hip/hip_runtime.h>
#include <float.h>

#define NLVL 12
#define NB   16
#define NBLK 256    // blocks for deg_hist / fill (per-block count arrays sized to this)

// meta: [96..109) base_f | [128..141) base_b | [160..177) base_o
// packed entry: id(18b) | fl(4b)<<18 | bl(4b)<<22 | tidx(4b)<<26   (N=200k < 2^18)
// tidx = nt*3+ninv in 0..8 -> h_init row = tabg[tidx]  (h_init never materialized)

struct Params {
    const int *nt, *ninv, *src, *dst, *fl, *bl, *batch;
    const float *We, *be, *Wf, *bf, *Wb, *bb;
    float *hN, *hB, *tabg, *out;
    int *rowptr, *cursor, *col, *nb_f, *nb_b, *onodes, *bsums, *meta, *plarr;
    int *cntf, *cntb, *cnto, *blkf, *blkb, *blko;
    int N, E, M, outN;
};

__device__ __forceinline__ float rlanef(float x, int l) {
    return __int_as_float(__builtin_amdgcn_readlane(__float_as_int(x), l));
}

// ---------------- degrees + per-block histograms + packed (fl,bl,tidx) -------
__global__ void k_deg_hist(Params p) {
    __shared__ int hf[NLVL], hb[NLVL], ho[NB];
    int tid = threadIdx.x, bid = blockIdx.x;
    if (tid < NLVL) { hf[tid] = 0; hb[tid] = 0; }
    if (tid < NB) ho[tid] = 0;
    __syncthreads();
    int g = bid * 256 + tid, gs = gridDim.x * 256;
    for (int e = g; e < p.E; e += gs) {               // fire-and-forget atomics
        atomicAdd(&p.rowptr[p.dst[e]], 1);
        atomicAdd(&p.rowptr[p.N + p.src[e]], 1);
    }
    // chunk-owned nodes (same chunk map as k_fill!)
    int chunk = (p.N + gridDim.x - 1) / gridDim.x;
    int lo = bid * chunk, hi = lo + chunk; if (hi > p.N) hi = p.N;
    for (int i = lo + tid; i < hi; i += 256) {
        int f = p.fl[i], b = p.bl[i];
        int t = p.nt[i], iv = p.ninv[i];
        p.plarr[i] = f | (b << 4) | ((t * 3 + iv) << 8);
        atomicAdd(&hf[f], 1);
        atomicAdd(&hb[b], 1);
        if (t == 1) atomicAdd(&ho[p.batch[i]], 1);
    }
    __syncthreads();
    if (tid < NLVL) { p.cntf[tid * NBLK + bid] = hf[tid]; p.cntb[tid * NBLK + bid] = hb[tid]; }
    if (tid < NB) p.cnto[tid * NBLK + bid] = ho[tid];
}

// ---------------- 3-kernel exclusive scan over M = 2N ----------------
__global__ void k_scan1(int* __restrict__ data, int M, int* __restrict__ bsums) {
    __shared__ int s[512];
    int t = threadIdx.x;
    int g = blockIdx.x * 512 + t;
    int v = (g < M) ? data[g] : 0;
    s[t] = v;
    __syncthreads();
    for (int off = 1; off < 512; off <<= 1) {
        int add = (t >= off) ? s[t - off] : 0;
        __syncthreads();
        s[t] += add;
        __syncthreads();
    }
    if (g < M) data[g] = s[t] - v;
    if (t == 511) bsums[blockIdx.x] = s[511];
}

// scan_top: bsums scan + per-block-base segmented scans + meta bases + tabg + out init
__global__ void k_scan_top(int* __restrict__ bsums, int nblk, Params p,
                           float* __restrict__ out, int outN) {
    __shared__ int s[1024];
    __shared__ int tot[48];     // fwd [0..12), bwd [16..28), out [32..48)
    int t = threadIdx.x;
    int* meta = p.meta;
    for (int i = t; i < outN; i += 1024)
        out[i] = ((i & 127) < 64) ? -FLT_MAX : 0.0f;   // max-pool init == finfo.min
    if (t < 576) {              // 9-row h_init table
        int row = t >> 6, j = t & 63;
        float nf = (float)(row / 3), iv = (float)(row % 3);
        p.tabg[t] = fmaf(nf, p.We[j], fmaf(iv, p.We[64 + j], p.be[j]));
    }
    int seg = t >> 8, b = t & 255;
    for (int r = 0; r < 3; r++) {
        int l = 4 * r + seg;
        int v = p.cntf[l * NBLK + b];
        s[t] = v; __syncthreads();
        for (int off = 1; off < NBLK; off <<= 1) {
            int add = (b >= off) ? s[t - off] : 0; __syncthreads();
            s[t] += add; __syncthreads();
        }
        p.blkf[l * NBLK + b] = s[t] - v;
        if (b == NBLK - 1) tot[l] = s[t];
        __syncthreads();
    }
    for (int r = 0; r < 3; r++) {
        int l = 4 * r + seg;
        int v = p.cntb[l * NBLK + b];
        s[t] = v; __syncthreads();
        for (int off = 1; off < NBLK; off <<= 1) {
            int add = (b >= off) ? s[t - off] : 0; __syncthreads();
            s[t] += add; __syncthreads();
        }
        p.blkb[l * NBLK + b] = s[t] - v;
        if (b == NBLK - 1) tot[16 + l] = s[t];
        __syncthreads();
    }
    for (int r = 0; r < 4; r++) {
        int l = 4 * r + seg;
        int v = p.cnto[l * NBLK + b];
        s[t] = v; __syncthreads();
        for (int off = 1; off < NBLK; off <<= 1) {
            int add = (b >= off) ? s[t - off] : 0; __syncthreads();
            s[t] += add; __syncthreads();
        }
        p.blko[l * NBLK + b] = s[t] - v;
        if (b == NBLK - 1) tot[32 + l] = s[t];
        __syncthreads();
    }
    if (t == 0) { int a = 0; for (int l = 0; l < NLVL; l++) { meta[96 + l] = a; a += tot[l]; } meta[96 + NLVL] = a; }
    if (t == 1) { int a = 0; for (int l = 0; l < NLVL; l++) { meta[128 + l] = a; a += tot[16 + l]; } meta[128 + NLVL] = a; }
    if (t == 2) { int a = 0; for (int l = 0; l < NB; l++) { meta[160 + l] = a; a += tot[32 + l]; } meta[160 + NB] = a; }
    __syncthreads();
    for (int i = t; i < NLVL * NBLK; i += 1024) p.blkf[i] += meta[96 + (i >> 8)];
    for (int i = t; i < NLVL * NBLK; i += 1024) p.blkb[i] += meta[128 + (i >> 8)];
    for (int i = t; i < NB * NBLK; i += 1024) p.blko[i] += meta[160 + (i >> 8)];
    int v = (t < nblk) ? bsums[t] : 0;
    s[t] = v;
    __syncthreads();
    for (int off = 1; off < 1024; off <<= 1) {
        int add = (t >= off) ? s[t - off] : 0;
        __syncthreads();
        s[t] += add;
        __syncthreads();
    }
    if (t < nblk) bsums[t] = s[t] - v;
}

__global__ void k_scan_add(int* __restrict__ rowptr, int* __restrict__ cursor, int M, int total,
                           const int* __restrict__ bsums) {
    int g = blockIdx.x * blockDim.x + threadIdx.x;
    if (g >= M) return;
    int r = rowptr[g] + bsums[g >> 9];
    rowptr[g] = r;
    cursor[g] = r;
    if (g == 0) rowptr[M] = total;
}

// ---------------- packed CSR fill + node scatter (LDS cursors) ----------------
__global__ void k_fill(Params p) {
    __shared__ int cur[48];     // fwd [0..12), bwd [16..28), out [32..48)
    int tid = threadIdx.x, bid = blockIdx.x;
    int g = bid * 256 + tid, gs = gridDim.x * 256;
    int N = p.N;

    // edge scatter (per-node cursor atomics: 196k distinct addresses, low contention)
    for (int e = g; e < p.E; e += gs) {
        int s = p.src[e], d = p.dst[e];
        p.col[atomicAdd(&p.cursor[d], 1)] = s | (p.plarr[s] << 18);      // in-edge: other = src
        p.col[atomicAdd(&p.cursor[N + s], 1)] = d | (p.plarr[d] << 18);  // out-edge: other = dst
    }

    // node scatter from precomputed per-block bases
    if (tid < NLVL) { cur[tid] = p.blkf[tid * NBLK + bid]; cur[16 + tid] = p.blkb[tid * NBLK + bid]; }
    if (tid < NB) cur[32 + tid] = p.blko[tid * NBLK + bid];
    __syncthreads();
    int chunk = (N + gridDim.x - 1) / gridDim.x;
    int lo = bid * chunk, hi = lo + chunk; if (hi > N) hi = N;
    for (int i = lo + tid; i < hi; i += 256) {
        int pl = p.plarr[i];
        int lf = pl & 15, lb = (pl >> 4) & 15, tx = (pl >> 8) & 15;
        int pk = i | (pl << 18);
        p.nb_f[atomicAdd(&cur[lf], 1)] = pk;
        p.nb_b[atomicAdd(&cur[16 + lb], 1)] = pk;
        if (tx >= 3 && tx < 6)                          // nt == 1
            p.onodes[atomicAdd(&cur[32 + p.batch[i]], 1)] = pk;
    }
}

// ---------------- per-level sweep: quarter-per-node gather + VALU matvec ----
// (zero DS ops; broadcast via v_readlane — champion r10/r11 code)
__global__ __launch_bounds__(256, 4) void k_sweep(Params p, int lvl, int dir) {
    const int tid = threadIdx.x, lane = tid & 63;
    const float* W = dir ? p.Wb : p.Wf;
    float w[64];
    #pragma unroll
    for (int k = 0; k < 64; k++) w[k] = W[k * 64 + lane];
    float bv = (dir ? p.bb : p.bf)[lane];

    const int* nb = dir ? p.nb_b : p.nb_f;
    const int* rp = p.rowptr + (dir ? p.N : 0);
    int start = p.meta[(dir ? 128 : 96) + lvl];
    int cnt   = p.meta[(dir ? 128 : 96) + lvl + 1] - start;
    const int wid = (blockIdx.x * 256 + tid) >> 6;
    const int nw  = (gridDim.x * 256) >> 6;
    const int q = lane >> 4, fb = (lane & 15) * 4;
    float* db = dir ? p.hB : p.hN;

    int c0 = (int)((long long)cnt * wid / nw);
    int c1 = (int)((long long)cnt * (wid + 1) / nw);
    for (int i = c0; i < c1; i += 4) {
        int my = i + q;
        int v = 0, rpv = 0, rpe = 0;
        if (my < c1) {
            int e = nb[start + my];
            v = e & 0x3FFFF;
            rpv = rp[v]; rpe = rp[v + 1];
        }
        float4 acc = make_float4(0.f, 0.f, 0.f, 0.f);
        for (int cb = rpv; cb < rpe; cb++) {
            int cu = p.col[cb];
            int u = cu & 0x3FFFF;
            int flu = (cu >> 18) & 15, blu = (cu >> 22) & 15;
            const float* sp;
            if (dir == 0)
                sp = (flu > 0 && flu < lvl) ? (p.hN + (size_t)u * 64)
                                            : (p.tabg + ((cu >> 26) & 15) * 64);
            else
                sp = (blu > 0 && blu < lvl) ? (p.hB + (size_t)u * 64)
                   : (flu > 0)              ? (p.hN + (size_t)u * 64)
                                            : (p.tabg + ((cu >> 26) & 15) * 64);
            const float4 x = *(const float4*)(sp + fb);
            acc.x += x.x; acc.y += x.y; acc.z += x.z; acc.w += x.w;
        }
        #pragma unroll
        for (int qq = 0; qq < 4; qq++) {
            if (i + qq >= c1) break;                    // wave-uniform
            int vs   = __builtin_amdgcn_readlane(v, 16 * qq);
            int degs = __builtin_amdgcn_readlane(rpe, 16 * qq)
                     - __builtin_amdgcn_readlane(rpv, 16 * qq);
            float o = bv * (float)degs;
            #pragma unroll
            for (int m = 0; m < 16; m++) {
                float ax = rlanef(acc.x, 16 * qq + m);
                float ay = rlanef(acc.y, 16 * qq + m);
                float az = rlanef(acc.z, 16 * qq + m);
                float aw = rlanef(acc.w, 16 * qq + m);
                o = fmaf(ax, w[4 * m + 0], o);
                o = fmaf(ay, w[4 * m + 1], o);
                o = fmaf(az, w[4 * m + 2], o);
                o = fmaf(aw, w[4 * m + 3], o);
            }
            db[(size_t)vs * 64 + lane] = o;
        }
    }
}

// ---------------- readout ----------------
__device__ inline void atomicMaxF(float* addr, float val) {
    int* ai = (int*)addr;
    int old = *ai;
    while (__int_as_float(old) < val) {
        int assumed = old;
        old = atomicCAS(ai, assumed, __float_as_int(val));
        if (old == assumed) break;
    }
}

__global__ void k_readout(Params p) {
    int lane = threadIdx.x & 63;
    int b = blockIdx.x >> 5;
    int sl = blockIdx.x & 31;
    int a0 = p.meta[160 + b], a1 = p.meta[161 + b];
    int cnt = a1 - a0;
    if (cnt == 0) return;
    int lo = a0 + (int)((long long)cnt * sl / 32);
    int hi = a0 + (int)((long long)cnt * (sl + 1) / 32);
    int wcnt = hi - lo;
    int wave = threadIdx.x >> 6;
    int wl = lo + (wcnt * wave) / 4;
    int wh = lo + (wcnt * (wave + 1)) / 4;
    if (wh <= wl) return;
    float mx = -FLT_MAX, sm = 0.f;
    for (int k = wl; k < wh; k += 64) {
        int take = wh - k; if (take > 64) take = 64;
        int el = (lane < take) ? p.onodes[k + lane] : 0;
        for (int j = 0; j < take; j++) {
            int e = __shfl(el, j, 64);
            int v = e & 0x3FFFF;
            int flv = (e >> 18) & 15, blv = (e >> 22) & 15;
            const float* sp = (blv > 0) ? (p.hB + (size_t)v * 64)
                            : (flv > 0) ? (p.hN + (size_t)v * 64)
                                        : (p.tabg + ((e >> 26) & 15) * 64);
            float x = sp[lane];
            mx = fmaxf(mx, x);
            sm += x;
        }
    }
    atomicMaxF(&p.out[b * 128 + lane], mx);
    atomicAdd(&p.out[b * 128 + 64 + lane], sm);
}

extern "C" void kernel_launch(void* const* d_in, const int* in_sizes, int n_in,
                              void* d_out, int out_size, void* d_ws, size_t ws_size,
                              hipStream_t stream) {
    int N = in_sizes[0];
    int E = in_sizes[2] / 2;
    int M = 2 * N;

    Params p;
    p.nt    = (const int*)d_in[0];
    p.ninv  = (const int*)d_in[1];
    p.src   = (const int*)d_in[2];
    p.dst   = (const int*)d_in[2] + E;
    p.fl    = (const int*)d_in[3];
    p.bl    = (const int*)d_in[4];
    p.batch = (const int*)d_in[5];
    p.We    = (const float*)d_in[6];
    p.be    = (const float*)d_in[7];
    p.Wf    = (const float*)d_in[8];
    p.bf    = (const float*)d_in[9];
    p.Wb    = (const float*)d_in[10];
    p.bb    = (const float*)d_in[11];
    p.out   = (float*)d_out;
    p.N = N; p.E = E; p.M = M; p.outN = out_size;

    char* ws = (char*)d_ws;
    size_t off = 0;
    auto alloc = [&](size_t bytes) -> char* {
        char* q = ws + off;
        off = (off + bytes + 255) & ~(size_t)255;
        return q;
    };
    // rowptr + meta adjacent -> one memset zeroes both
    p.rowptr = (int*)  alloc((size_t)(M + 1) * sizeof(int));
    p.meta   = (int*)  alloc(256 * sizeof(int));
    size_t zbytes = (size_t)((char*)(p.meta + 256) - (char*)p.rowptr);
    p.hN     = (float*)alloc((size_t)N * 64 * sizeof(float));
    p.hB     = (float*)alloc((size_t)N * 64 * sizeof(float));
    p.tabg   = (float*)alloc(9 * 64 * sizeof(float));
    p.cursor = (int*)  alloc((size_t)M * sizeof(int));
    p.col    = (int*)  alloc((size_t)2 * E * sizeof(int));
    p.nb_f   = (int*)  alloc((size_t)N * sizeof(int));
    p.nb_b   = (int*)  alloc((size_t)N * sizeof(int));
    p.onodes = (int*)  alloc((size_t)N * sizeof(int));
    p.plarr  = (int*)  alloc((size_t)N * sizeof(int));
    p.bsums  = (int*)  alloc(1024 * sizeof(int));
    p.cntf   = (int*)  alloc(NLVL * NBLK * sizeof(int));
    p.cntb   = (int*)  alloc(NLVL * NBLK * sizeof(int));
    p.cnto   = (int*)  alloc(NB * NBLK * sizeof(int));
    p.blkf   = (int*)  alloc(NLVL * NBLK * sizeof(int));
    p.blkb   = (int*)  alloc(NLVL * NBLK * sizeof(int));
    p.blko   = (int*)  alloc(NB * NBLK * sizeof(int));

    int nscan = (M + 511) / 512;            // 782 <= 1024

    hipMemsetAsync(p.rowptr, 0, zbytes, stream);
    k_deg_hist<<<NBLK, 256, 0, stream>>>(p);
    k_scan1<<<nscan, 512, 0, stream>>>(p.rowptr, M, p.bsums);
    k_scan_top<<<1, 1024, 0, stream>>>(p.bsums, nscan, p, p.out, out_size);
    k_scan_add<<<(M + 255) / 256, 256, 0, stream>>>(p.rowptr, p.cursor, M, 2 * E, p.bsums);
    k_fill<<<NBLK, 256, 0, stream>>>(p);

    for (int l = 1; l < NLVL; l++)
        k_sweep<<<1024, 256, 0, stream>>>(p, l, 0);
    for (int l = 1; l < NLVL; l++)
        k_sweep<<<1024, 256, 0, stream>>>(p, l, 1);

    k_readout<<<NB * 32, 256, 0, stream>>>(p);
}